// Round 5
// baseline (46736.121 us; speedup 1.0000x reference)
//
#include <hip/hip_runtime.h>

typedef unsigned short u16;
typedef unsigned int u32;

#define NT 1024
#define NB 32
#define Bv 32
#define Tv 256
#define Wv 128
#define Rv 4
#define Nv 128
#define DELTAv 1e-6f

// hE_T/hC_T swizzled LDS index: value (w, b) at w*32 + ((b+w)&31)
#define HSW(w,b) (((w) << 5) + (((b) + (w)) & 31))

__device__ __forceinline__ float bf2f(u16 u){
  union { u32 i; float f; } c; c.i = ((u32)u) << 16; return c.f;
}
__device__ __forceinline__ u16 f2bf(float f){
  union { float f; u32 u; } c; c.f = f;
  u32 u = c.u;
  return (u16)((u + 0x7fffu + ((u >> 16) & 1u)) >> 16);
}
__device__ __forceinline__ void unp(u32 v, float& a, float& b){
  union { u32 i; float f; } c0, c1;
  c0.i = v << 16; c1.i = v & 0xffff0000u;
  a = c0.f; b = c1.f;
}
__device__ __forceinline__ float sigm(float x){ return 1.0f / (1.0f + __expf(-x)); }
__device__ __forceinline__ float softplusf(float x){ return fmaxf(x, 0.f) + log1pf(__expf(-fabsf(x))); }
__device__ __forceinline__ float wredsum(float v){
  #pragma unroll
  for (int o = 32; o > 0; o >>= 1) v += __shfl_down(v, o, 64);
  return v;
}
__device__ __forceinline__ float wredmax(float v){
  #pragma unroll
  for (int o = 32; o > 0; o >>= 1) v = fmaxf(v, __shfl_down(v, o, 64));
  return v;
}
__device__ __forceinline__ float ldval(const void* p, int idx, int dt32){
  return dt32 ? ((const float*)p)[idx] : bf2f(((const u16*)p)[idx]);
}

// ---- dtype detect (flag=1 -> fp32 tensors, 0 -> bf16) ----
__global__ void detect_dtype(const u16* __restrict__ buf, int* __restrict__ flag){
  int lane = threadIdx.x;
  float crazy = 0.f;
  for (int i = 0; i < 4; i++){
    u16 v = buf[lane * 4 + i];
    int e = (v >> 7) & 0xFF;
    if (e != 0 && (e < 117 || e > 137)) crazy += 1.f;
  }
  crazy = wredsum(crazy);
  if (lane == 0) flag[0] = (crazy >= 32.f) ? 1 : 0;
}

// identity-column pack: dst[k2*Jd + j] = bf16pair(W[j][2k2], W[j][2k2+1])
__global__ void pack_w(const void* __restrict__ src, u32* __restrict__ dst,
                       int Js, int Jd, int K, const int* __restrict__ flag){
  int j = blockIdx.x * 256 + threadIdx.x;
  int k2 = blockIdx.y;
  if (j >= Jd) return;
  u16 lo = 0, hi = 0;
  if (j < Js){
    if (flag[0]){
      const float* s = (const float*)src;
      lo = f2bf(s[(size_t)j * K + 2 * k2]);
      hi = f2bf(s[(size_t)j * K + 2 * k2 + 1]);
    } else {
      const u16* s = (const u16*)src;
      lo = s[(size_t)j * K + 2 * k2];
      hi = s[(size_t)j * K + 2 * k2 + 1];
    }
  }
  dst[(size_t)k2 * Jd + j] = (u32)lo | ((u32)hi << 16);
}

__device__ __forceinline__ int permctl(int c){
  // packed ctl col -> original interleaved col: [hE(128); rv r-major(512)]
  if (c < 128) return 5 * c;
  int q = c - 128; return 5 * (q & 127) + 1 + (q >> 7);
}
__device__ __forceinline__ int permout(int c){
  // packed out col -> original col: [h(128); rv w-major(512)]
  if (c < 128) return c;
  int q = c - 128; return 128 + 4 * (q & 127) + (q >> 7);
}

__global__ void pack_ctl(const void* __restrict__ src, u32* __restrict__ dst,
                         const int* __restrict__ flag){
  int j = blockIdx.x * 256 + threadIdx.x;   // 512 rows
  int k2 = blockIdx.y;                      // 320 pairs
  if (j >= 512) return;
  int c0 = permctl(2 * k2), c1 = permctl(2 * k2 + 1);
  u16 lo, hi;
  if (flag[0]){
    const float* s = (const float*)src;
    lo = f2bf(s[(size_t)j * 640 + c0]); hi = f2bf(s[(size_t)j * 640 + c1]);
  } else {
    const u16* s = (const u16*)src;
    lo = s[(size_t)j * 640 + c0]; hi = s[(size_t)j * 640 + c1];
  }
  dst[(size_t)k2 * 512 + j] = (u32)lo | ((u32)hi << 16);
}

__global__ void pack_out(const void* __restrict__ src, u32* __restrict__ dst,
                         const int* __restrict__ flag){
  int j = blockIdx.x * 128 + threadIdx.x;   // 128 rows
  int k2 = blockIdx.y;                      // 320 pairs
  if (j >= 128) return;
  int c0 = permout(2 * k2), c1 = permout(2 * k2 + 1);
  u16 lo, hi;
  if (flag[0]){
    const float* s = (const float*)src;
    lo = f2bf(s[(size_t)j * 640 + c0]); hi = f2bf(s[(size_t)j * 640 + c1]);
  } else {
    const u16* s = (const u16*)src;
    lo = s[(size_t)j * 640 + c0]; hi = s[(size_t)j * 640 + c1];
  }
  dst[(size_t)k2 * 128 + j] = (u32)lo | ((u32)hi << 16);
}

__global__ void zero_i32(int* __restrict__ p, int n){
  int i = blockIdx.x * 256 + threadIdx.x;
  if (i < n) p[i] = 0;
}

__global__ void fill_half(u16* __restrict__ p, int n){
  int i = blockIdx.x * 256 + threadIdx.x;
  if (i < n) p[i] = 0x3F00;
}

// grid barrier: 32 per-block flag words, 128B-strided; monotone rounds
__device__ __forceinline__ void gridbar(int* flags, int bid, int tid, int round){
  __syncthreads();                 // each wave drains its own vmcnt before s_barrier
  if (tid == 0)
    __hip_atomic_store(flags + bid * 32, round, __ATOMIC_RELEASE, __HIP_MEMORY_SCOPE_AGENT);
  if (tid < NB){
    while (__hip_atomic_load(flags + tid * 32, __ATOMIC_ACQUIRE, __HIP_MEMORY_SCOPE_AGENT) < round)
      __builtin_amdgcn_s_sleep(2);
  }
  __syncthreads();
}

__global__ __launch_bounds__(NT) void dnc_main(
    const void* __restrict__ input,
    const void* __restrict__ enc_bih_g, const void* __restrict__ enc_bhh_g,
    const void* __restrict__ ctl_bih_g, const void* __restrict__ ctl_bhh_g,
    const void* __restrict__ iface_b_g, const void* __restrict__ out_b_g,
    const u32* __restrict__ encPW, const u32* __restrict__ ctlPW,
    const u32* __restrict__ ifPW, const u32* __restrict__ outPW,
    float* G1T, float* G2T, float* XIT, float* RVT,
    float* __restrict__ linkG, float* __restrict__ linkTG,
    int* flags, void* __restrict__ outp, const int* __restrict__ dtflag)
{
  const int bid = blockIdx.x;     // = owner batch
  const int tid = threadIdx.x;
  const int lane = tid & 63;
  const int wid = tid >> 6;
  const int dt32 = dtflag[0];

  __shared__ __align__(16) float memS[Nv * 129];   // 66048 B (pad 129)
  __shared__ __align__(16) float hET[4096];        // replicated enc h, swizzled [w][b]
  __shared__ __align__(16) float hCT[4096];        // replicated ctl h
  __shared__ __align__(16) u32   RVp[8192];        // all-batch rv, bf16 pairs [p][b]
  __shared__ __align__(16) float pp[NT];
  __shared__ __align__(16) float rkeyS[512], rwS[512], rcS[512], fwS[512];
  __shared__ __align__(16) float wkeyS[128], eraseS[128], wvecS[128];
  __shared__ __align__(16) float wwS[128], usageS[128], precS[128], wcS[128];
  __shared__ __align__(16) float uS[128], sortedU[128], scanA[128];
  __shared__ float rstrS[4], fgS[4], rmRaw[12], rmS[12], scal[8];

  float* linkB = linkG + (size_t)bid * Nv * Nv;
  float* linkTB = linkTG + (size_t)bid * Nv * Nv;

  // ---- init ----
  for (int i = tid; i < Nv * 129; i += NT) memS[i] = 0.f;
  for (int i = tid; i < 4096; i += NT){ hET[i] = 0.f; hCT[i] = 0.f; }
  for (int i = tid; i < 8192; i += NT) RVp[i] = 0;
  if (tid < 512) rwS[tid] = 0.f;
  if (tid < 128){ wwS[tid] = 0.f; usageS[tid] = 0.f; precS[tid] = 0.f; }
  for (int i = tid; i < Nv * Nv; i += NT){ linkB[i] = 0.f; linkTB[i] = 0.f; }
  if (tid < 512)
    __hip_atomic_store(RVT + tid * 32 + bid, 0.f, __ATOMIC_RELAXED, __HIP_MEMORY_SCOPE_AGENT);
  float cE[4] = {0.f, 0.f, 0.f, 0.f};
  float cC[4] = {0.f, 0.f, 0.f, 0.f};
  int round = 1;
  __syncthreads();

  for (int t = 0; t < Tv; ++t){
    // ================= P1: encoder gates GEMM (cross-batch tile) =================
    {
      int s = tid >> 9, o = (tid >> 5) & 15, b = tid & 31;
      int og = (bid << 4) + o;
      float acc = 0.f;
      if (s == 0){
        int base = (b * Tv + t) * Wv;
        const u32* wp = encPW + og;
        if (dt32){
          const float2* xp = (const float2*)((const float*)input + base);
          #pragma unroll 8
          for (int k2 = 0; k2 < 64; k2++){
            float w0, w1; unp(wp[k2 * 512], w0, w1);
            float2 x2 = xp[k2];
            acc += x2.x * w0 + x2.y * w1;
          }
        } else {
          const u32* xp = (const u32*)((const u16*)input + base);
          #pragma unroll 8
          for (int k2 = 0; k2 < 64; k2++){
            float w0, w1; unp(wp[k2 * 512], w0, w1);
            float x0, x1; unp(xp[k2], x0, x1);
            acc += x0 * w0 + x1 * w1;
          }
        }
      } else {
        const u32* wp = encPW + 64 * 512 + og;
        #pragma unroll 8
        for (int k2 = 0; k2 < 64; k2++){
          float h0 = hET[HSW(2 * k2, b)], h1 = hET[HSW(2 * k2 + 1, b)];
          float w0, w1; unp(wp[k2 * 512], w0, w1);
          acc += h0 * w0 + h1 * w1;
        }
      }
      pp[tid] = acc;
    }
    __syncthreads();
    if (tid < 512){
      int o = tid >> 5, b = tid & 31;
      int og = (bid << 4) + o;
      __hip_atomic_store(G1T + og * 32 + b, pp[tid] + pp[512 + tid],
                         __ATOMIC_RELAXED, __HIP_MEMORY_SCOPE_AGENT);
    }
    gridbar(flags, bid, tid, round++);   // GB1

    // ================= P2: enc pointwise (replicated) + ctl GEMM =================
    {
      int b = tid & 31, w0 = tid >> 5;
      #pragma unroll
      for (int k = 0; k < 4; k++){
        int w = w0 + k * 32;
        float gi = __hip_atomic_load(G1T + (0 * 128 + w) * 32 + b, __ATOMIC_RELAXED, __HIP_MEMORY_SCOPE_AGENT)
                 + ldval(enc_bih_g, 0 * 128 + w, dt32) + ldval(enc_bhh_g, 0 * 128 + w, dt32);
        float gf = __hip_atomic_load(G1T + (1 * 128 + w) * 32 + b, __ATOMIC_RELAXED, __HIP_MEMORY_SCOPE_AGENT)
                 + ldval(enc_bih_g, 1 * 128 + w, dt32) + ldval(enc_bhh_g, 1 * 128 + w, dt32);
        float gg = __hip_atomic_load(G1T + (2 * 128 + w) * 32 + b, __ATOMIC_RELAXED, __HIP_MEMORY_SCOPE_AGENT)
                 + ldval(enc_bih_g, 2 * 128 + w, dt32) + ldval(enc_bhh_g, 2 * 128 + w, dt32);
        float go = __hip_atomic_load(G1T + (3 * 128 + w) * 32 + b, __ATOMIC_RELAXED, __HIP_MEMORY_SCOPE_AGENT)
                 + ldval(enc_bih_g, 3 * 128 + w, dt32) + ldval(enc_bhh_g, 3 * 128 + w, dt32);
        float cn = sigm(gf) * cE[k] + sigm(gi) * tanhf(gg);
        cE[k] = cn;
        hET[HSW(w, b)] = sigm(go) * tanhf(cn);
      }
    }
    __syncthreads();
    {
      int s = tid >> 9, o = (tid >> 5) & 15, b = tid & 31;
      int og = (bid << 4) + o;
      const u32* wp = ctlPW + og;
      float acc = 0.f;
      if (s == 0){
        #pragma unroll 8
        for (int k2 = 0; k2 < 64; k2++){
          float h0 = hET[HSW(2 * k2, b)], h1 = hET[HSW(2 * k2 + 1, b)];
          float w0, w1; unp(wp[k2 * 512], w0, w1);
          acc += h0 * w0 + h1 * w1;
        }
        #pragma unroll 8
        for (int k2 = 64; k2 < 192; k2++){
          float x0, x1; unp(RVp[(k2 - 64) * 32 + b], x0, x1);
          float w0, w1; unp(wp[k2 * 512], w0, w1);
          acc += x0 * w0 + x1 * w1;
        }
      } else {
        #pragma unroll 8
        for (int k2 = 192; k2 < 320; k2++){
          float x0, x1; unp(RVp[(k2 - 64) * 32 + b], x0, x1);
          float w0, w1; unp(wp[k2 * 512], w0, w1);
          acc += x0 * w0 + x1 * w1;
        }
        #pragma unroll 8
        for (int k2 = 320; k2 < 384; k2++){
          int w = 2 * (k2 - 320);
          float h0 = hCT[HSW(w, b)], h1 = hCT[HSW(w + 1, b)];
          float w0, w1; unp(wp[k2 * 512], w0, w1);
          acc += h0 * w0 + h1 * w1;
        }
      }
      pp[tid] = acc;
    }
    __syncthreads();
    if (tid < 512){
      int o = tid >> 5, b = tid & 31;
      int og = (bid << 4) + o;
      __hip_atomic_store(G2T + og * 32 + b, pp[tid] + pp[512 + tid],
                         __ATOMIC_RELAXED, __HIP_MEMORY_SCOPE_AGENT);
    }
    gridbar(flags, bid, tid, round++);   // GB2

    // ================= P3: ctl pointwise (replicated) + iface GEMM =================
    {
      int b = tid & 31, w0 = tid >> 5;
      #pragma unroll
      for (int k = 0; k < 4; k++){
        int w = w0 + k * 32;
        float gi = __hip_atomic_load(G2T + (0 * 128 + w) * 32 + b, __ATOMIC_RELAXED, __HIP_MEMORY_SCOPE_AGENT)
                 + ldval(ctl_bih_g, 0 * 128 + w, dt32) + ldval(ctl_bhh_g, 0 * 128 + w, dt32);
        float gf = __hip_atomic_load(G2T + (1 * 128 + w) * 32 + b, __ATOMIC_RELAXED, __HIP_MEMORY_SCOPE_AGENT)
                 + ldval(ctl_bih_g, 1 * 128 + w, dt32) + ldval(ctl_bhh_g, 1 * 128 + w, dt32);
        float gg = __hip_atomic_load(G2T + (2 * 128 + w) * 32 + b, __ATOMIC_RELAXED, __HIP_MEMORY_SCOPE_AGENT)
                 + ldval(ctl_bih_g, 2 * 128 + w, dt32) + ldval(ctl_bhh_g, 2 * 128 + w, dt32);
        float go = __hip_atomic_load(G2T + (3 * 128 + w) * 32 + b, __ATOMIC_RELAXED, __HIP_MEMORY_SCOPE_AGENT)
                 + ldval(ctl_bih_g, 3 * 128 + w, dt32) + ldval(ctl_bhh_g, 3 * 128 + w, dt32);
        float cn = sigm(gf) * cC[k] + sigm(gi) * tanhf(gg);
        cC[k] = cn;
        hCT[HSW(w, b)] = sigm(go) * tanhf(cn);
      }
    }
    __syncthreads();
    if (tid < 928){
      int o = tid >> 5, b = tid & 31;
      int og = bid * 29 + o;
      const u32* wp = ifPW + og;
      float acc = (og < 919) ? ldval(iface_b_g, og, dt32) : 0.f;
      #pragma unroll 8
      for (int k2 = 0; k2 < 64; k2++){
        float h0 = hCT[HSW(2 * k2, b)], h1 = hCT[HSW(2 * k2 + 1, b)];
        float w0, w1; unp(wp[k2 * 928], w0, w1);
        acc += h0 * w0 + h1 * w1;
      }
      __hip_atomic_store(XIT + og * 32 + b, acc, __ATOMIC_RELAXED, __HIP_MEMORY_SCOPE_AGENT);
    }
    gridbar(flags, bid, tid, round++);   // GB3

    // ================= P4: per-batch memory machinery (own batch) =================
    // a: parse interface
    if (tid < 919){
      float v = __hip_atomic_load(XIT + tid * 32 + bid, __ATOMIC_RELAXED, __HIP_MEMORY_SCOPE_AGENT);
      if (tid < 512) rkeyS[tid] = tanhf(v);
      else if (tid < 516) rstrS[tid - 512] = softplusf(v);
      else if (tid < 644) wkeyS[tid - 516] = tanhf(v);
      else if (tid == 644) scal[0] = softplusf(v);
      else if (tid < 773) eraseS[tid - 645] = sigm(v);
      else if (tid < 901) wvecS[tid - 773] = tanhf(v);
      else if (tid < 905) fgS[tid - 901] = sigm(v);
      else if (tid == 905) scal[1] = sigm(v);
      else if (tid == 906) scal[2] = sigm(v);
      else rmRaw[tid - 907] = v;
    }
    __syncthreads();
    // b: key norms + usage (old ww/rw) + read-mode softmax
    if (wid < 5){
      float* arr = (wid < 4) ? (rkeyS + wid * 128) : wkeyS;
      float a = arr[lane], bq = arr[lane + 64];
      float s = wredsum(a * a + bq * bq);
      s = __shfl(s, 0, 64);
      float inv = 1.0f / (sqrtf(s) + DELTAv);
      arr[lane] = a * inv; arr[lane + 64] = bq * inv;
    } else if (wid < 7){
      int n = (wid - 5) * 64 + lane;
      float us = usageS[n];
      us = us + (1.f - us) * wwS[n];
      float ret = (1.f - fgS[0] * rwS[n]) * (1.f - fgS[1] * rwS[128 + n]) *
                  (1.f - fgS[2] * rwS[256 + n]) * (1.f - fgS[3] * rwS[384 + n]);
      usageS[n] = us * ret;
    } else if (tid >= 448 && tid < 452){
      int r = tid - 448;
      float m0 = rmRaw[3 * r], m1 = rmRaw[3 * r + 1], m2 = rmRaw[3 * r + 2];
      float mx = fmaxf(m0, fmaxf(m1, m2));
      float e0 = __expf(m0 - mx), e1 = __expf(m1 - mx), e2 = __expf(m2 - mx);
      float s = e0 + e1 + e2;
      rmS[3 * r] = e0 / s; rmS[3 * r + 1] = e1 / s; rmS[3 * r + 2] = e2 / s;
    }
    __syncthreads();
    // c: write-content dots (old mem) + uS
    if (tid < 128){
      float sq = 0.f, dt = 0.f;
      #pragma unroll 8
      for (int j = 0; j < 128; j++){
        float m = memS[tid * 129 + j];
        sq += m * m; dt += m * wkeyS[j];
      }
      wcS[tid] = dt / (sqrtf(sq) + DELTAv) * scal[0];
    } else if (tid < 256){
      uS[tid - 128] = DELTAv + (1.f - DELTAv) * usageS[tid - 128];
    }
    __syncthreads();
    // d: wc softmax (wave0) + stable rank (tid 64..191)
    int rnk = 0;
    if (wid == 0){
      float a = wcS[lane], bq = wcS[lane + 64];
      float mx = wredmax(fmaxf(a, bq)); mx = __shfl(mx, 0, 64);
      float ea = __expf(a - mx), eb = __expf(bq - mx);
      float s = wredsum(ea + eb); s = __shfl(s, 0, 64);
      wcS[lane] = ea / s; wcS[lane + 64] = eb / s;
    } else if (tid >= 64 && tid < 192){
      int n = tid - 64;
      float un = uS[n];
      int r = 0;
      for (int m = 0; m < 128; m++){
        float um = uS[m];
        r += (um < un) || (um == un && m < n);
      }
      rnk = r;
      sortedU[r] = un;
    }
    __syncthreads();
    // e: inclusive cumprod scan (wave 8)
    if (wid == 8){
      float a = sortedU[2 * lane], bq = sortedU[2 * lane + 1];
      float p = a * bq;
      float incl = p;
      #pragma unroll
      for (int o = 1; o < 64; o <<= 1){
        float tv = __shfl_up(incl, o, 64);
        if (lane >= o) incl *= tv;
      }
      float ex = __shfl_up(incl, 1, 64);
      if (lane == 0) ex = 1.f;
      scanA[2 * lane] = ex * a;
      scanA[2 * lane + 1] = ex * p;
    }
    __syncthreads();
    // f: alloc + write weighting
    if (tid >= 64 && tid < 192){
      int n = tid - 64;
      float ex = (rnk == 0) ? 1.f : scanA[rnk - 1];
      float al = (1.f - uS[n]) * ex;
      wwS[n] = scal[2] * (scal[1] * al + (1.f - scal[1]) * wcS[n]);
    }
    __syncthreads();
    // g: sum ww
    if (wid == 0){
      float s = wredsum(wwS[lane] + wwS[64 + lane]);
      if (lane == 0) scal[3] = s;
    }
    __syncthreads();
    // h: mem erase/write (LDS) + link/linkT update (old prec)
    #pragma unroll
    for (int it = 0; it < 16; it++){
      int idx = it * NT + tid;
      int n = idx >> 7, w = idx & 127;
      float wwn = wwS[n];
      float m = memS[n * 129 + w];
      memS[n * 129 + w] = m * (1.f - wwn * eraseS[w]) + wwn * wvecS[w];
    }
    {
      float4* l4 = (float4*)linkB;
      #pragma unroll
      for (int it = 0; it < 4; it++){
        int e4 = it * NT + tid;
        int n = e4 >> 5, w0 = (e4 & 31) * 4;
        float wwn = wwS[n];
        float4 l = l4[e4];
        float v0 = (n == w0 + 0) ? 0.f : ((1.f - wwn - wwS[w0 + 0]) * l.x + wwn * precS[w0 + 0]);
        float v1 = (n == w0 + 1) ? 0.f : ((1.f - wwn - wwS[w0 + 1]) * l.y + wwn * precS[w0 + 1]);
        float v2 = (n == w0 + 2) ? 0.f : ((1.f - wwn - wwS[w0 + 2]) * l.z + wwn * precS[w0 + 2]);
        float v3 = (n == w0 + 3) ? 0.f : ((1.f - wwn - wwS[w0 + 3]) * l.w + wwn * precS[w0 + 3]);
        l4[e4] = make_float4(v0, v1, v2, v3);
        linkTB[(w0 + 0) * 128 + n] = v0;
        linkTB[(w0 + 1) * 128 + n] = v1;
        linkTB[(w0 + 2) * 128 + n] = v2;
        linkTB[(w0 + 3) * 128 + n] = v3;
      }
    }
    __syncthreads();
    // i: read-content dots (new mem) + prec update
    if (tid < 128){
      float sq = 0.f, d0 = 0.f, d1 = 0.f, d2 = 0.f, d3 = 0.f;
      #pragma unroll 4
      for (int j = 0; j < 128; j++){
        float m = memS[tid * 129 + j];
        sq += m * m;
        d0 += m * rkeyS[j];
        d1 += m * rkeyS[128 + j];
        d2 += m * rkeyS[256 + j];
        d3 += m * rkeyS[384 + j];
      }
      float inv = 1.f / (sqrtf(sq) + DELTAv);
      rcS[tid]       = d0 * inv * rstrS[0];
      rcS[128 + tid] = d1 * inv * rstrS[1];
      rcS[256 + tid] = d2 * inv * rstrS[2];
      rcS[384 + tid] = d3 * inv * rstrS[3];
    } else if (tid < 256){
      int n = tid - 128;
      precS[n] = (1.f - scal[3]) * precS[n] + wwS[n];
    }
    __syncthreads();
    // j: rc softmax (waves 0-3)
    if (wid < 4){
      float a = rcS[wid * 128 + lane], bq = rcS[wid * 128 + 64 + lane];
      float mx = wredmax(fmaxf(a, bq)); mx = __shfl(mx, 0, 64);
      float ea = __expf(a - mx), eb = __expf(bq - mx);
      float s = wredsum(ea + eb); s = __shfl(s, 0, 64);
      rcS[wid * 128 + lane] = ea / s; rcS[wid * 128 + 64 + lane] = eb / s;
    }
    __syncthreads();
    // k: fw (linkT cols) / bw (link cols), old rw — coalesced per-thread dots
    if (tid < 512){
      int r = tid >> 7, i = tid & 127;
      float acc = 0.f;
      #pragma unroll 8
      for (int j = 0; j < 128; j++) acc += rwS[r * 128 + j] * linkTB[j * 128 + i];
      fwS[tid] = acc;
    } else {
      int o = tid - 512, r = o >> 7, i = o & 127;
      float acc = 0.f;
      #pragma unroll 8
      for (int j = 0; j < 128; j++) acc += rwS[r * 128 + j] * linkB[j * 128 + i];
      pp[o] = acc;   // bw
    }
    __syncthreads();
    // l: new read weights
    if (tid < 512){
      int r = tid >> 7;
      rwS[tid] = rmS[3 * r] * pp[tid] + rmS[3 * r + 1] * fwS[tid] + rmS[3 * r + 2] * rcS[tid];
    }
    __syncthreads();
    // m: rv partials
    {
      int s = tid >> 9, o = tid & 511, r = o >> 7, w = o & 127;
      float acc = 0.f;
      #pragma unroll 8
      for (int q = 0; q < 64; q++){
        int n = s * 64 + q;
        acc += rwS[r * 128 + n] * memS[n * 129 + w];
      }
      pp[tid] = acc;
    }
    __syncthreads();
    // n: rv combine -> RV_T (sc1)
    if (tid < 512)
      __hip_atomic_store(RVT + tid * 32 + bid, pp[tid] + pp[512 + tid],
                         __ATOMIC_RELAXED, __HIP_MEMORY_SCOPE_AGENT);
    gridbar(flags, bid, tid, round++);   // GB4

    // ================= P5: stage RVp (all batches) + output GEMM =================
    #pragma unroll
    for (int i = 0; i < 8; i++){
      int idx = i * NT + tid;
      int p = idx >> 5, b = idx & 31;
      float v0 = __hip_atomic_load(RVT + (2 * p) * 32 + b, __ATOMIC_RELAXED, __HIP_MEMORY_SCOPE_AGENT);
      float v1 = __hip_atomic_load(RVT + (2 * p + 1) * 32 + b, __ATOMIC_RELAXED, __HIP_MEMORY_SCOPE_AGENT);
      RVp[idx] = (u32)f2bf(v0) | ((u32)f2bf(v1) << 16);
    }
    __syncthreads();
    {
      int s = tid >> 7, o = (tid >> 5) & 3, b = tid & 31;
      int og = (bid << 2) + o;
      const u32* wp = outPW + og;
      float acc = 0.f;
      int lo = s * 40, hi = lo + 40;
      for (int k2 = lo; k2 < hi; k2++){
        float x0, x1;
        if (k2 < 64){ x0 = hCT[HSW(2 * k2, b)]; x1 = hCT[HSW(2 * k2 + 1, b)]; }
        else { unp(RVp[(k2 - 64) * 32 + b], x0, x1); }
        float w0, w1; unp(wp[k2 * 128], w0, w1);
        acc += x0 * w0 + x1 * w1;
      }
      pp[tid] = acc;
    }
    __syncthreads();
    if (tid < 128){
      int o = tid >> 5, b = tid & 31;
      int og = (bid << 2) + o;
      float acc = ldval(out_b_g, og, dt32);
      #pragma unroll
      for (int s = 0; s < 8; s++) acc += pp[s * 128 + o * 32 + b];
      size_t oi = ((size_t)b * Tv + t) * Wv + og;
      if (dt32) ((float*)outp)[oi] = acc;
      else ((u16*)outp)[oi] = f2bf(acc);
    }
    __syncthreads();   // protect pp before next P1
  }
}

extern "C" void kernel_launch(void* const* d_in, const int* in_sizes, int n_in,
                              void* d_out, int out_size, void* d_ws, size_t ws_size,
                              hipStream_t stream) {
  (void)in_sizes; (void)n_in;
  const void* input   = d_in[0];
  const void* enc_Wih = d_in[2];
  const void* enc_Whh = d_in[3];
  const void* enc_bih = d_in[4];
  const void* enc_bhh = d_in[5];
  const void* ctl_Wih = d_in[6];
  const void* ctl_Whh = d_in[7];
  const void* ctl_bih = d_in[8];
  const void* ctl_bhh = d_in[9];
  const void* iface_W = d_in[10];
  const void* iface_b = d_in[11];
  const void* out_W   = d_in[12];
  const void* out_b   = d_in[13];

  char* ws = (char*)d_ws;
  size_t off = 0;
  int* dtflag = (int*)(ws + off); off += 256;
  int* flags  = (int*)(ws + off); off += 4096;          // 32 blocks x 128B stride
  float* G1T  = (float*)(ws + off); off += 512 * 32 * 4;
  float* G2T  = (float*)(ws + off); off += 512 * 32 * 4;
  float* XIT  = (float*)(ws + off); off += 928 * 32 * 4;
  float* RVT  = (float*)(ws + off); off += 512 * 32 * 4;
  u32* encPW  = (u32*)(ws + off); off += (size_t)128 * 512 * 4;
  u32* ctlPW  = (u32*)(ws + off); off += (size_t)384 * 512 * 4;
  u32* ifPW   = (u32*)(ws + off); off += (size_t)64 * 928 * 4;
  u32* outPW  = (u32*)(ws + off); off += (size_t)320 * 128 * 4;
  float* linkG  = (float*)(ws + off); off += (size_t)Bv * Nv * Nv * 4;
  float* linkTG = (float*)(ws + off); off += (size_t)Bv * Nv * Nv * 4;
  const size_t need_bytes = off;   // ~5.97 MB

  if (ws_size < need_bytes){
    fill_half<<<dim3((out_size + 255) / 256), dim3(256), 0, stream>>>((u16*)d_out, out_size);
    return;
  }

  detect_dtype<<<dim3(1), dim3(64), 0, stream>>>((const u16*)input, dtflag);
  zero_i32<<<dim3(4), dim3(256), 0, stream>>>(flags, 1024);

  pack_w<<<dim3(2, 64), 256, 0, stream>>>(enc_Wih, encPW, 512, 512, 128, dtflag);
  pack_w<<<dim3(2, 64), 256, 0, stream>>>(enc_Whh, encPW + 64 * 512, 512, 512, 128, dtflag);
  pack_ctl<<<dim3(2, 320), 256, 0, stream>>>(ctl_Wih, ctlPW, dtflag);
  pack_w<<<dim3(2, 64), 256, 0, stream>>>(ctl_Whh, ctlPW + 320 * 512, 512, 512, 128, dtflag);
  pack_w<<<dim3(4, 64), 256, 0, stream>>>(iface_W, ifPW, 919, 928, 128, dtflag);
  pack_out<<<dim3(1, 320), 128, 0, stream>>>(out_W, outPW, dtflag);

  dnc_main<<<dim3(NB), dim3(NT), 0, stream>>>(
      input, enc_bih, enc_bhh, ctl_bih, ctl_bhh, iface_b, out_b,
      encPW, ctlPW, ifPW, outPW,
      G1T, G2T, XIT, RVT, linkG, linkTG, flags, d_out, dtflag);
}

// Round 6
// 11211.643 us; speedup vs baseline: 4.1685x; 4.1685x over previous
//
#include <hip/hip_runtime.h>

typedef unsigned short u16;
typedef unsigned int u32;

#define NT 1024
#define Bv 32
#define Tv 256
#define Wv 128
#define Rv 4
#define Nv 128
#define DELTAv 1e-6f

__device__ __forceinline__ float bf2f(u16 u){
  union { u32 i; float f; } c; c.i = ((u32)u) << 16; return c.f;
}
__device__ __forceinline__ u16 f2bf(float f){
  union { float f; u32 u; } c; c.f = f;
  u32 u = c.u;
  return (u16)((u + 0x7fffu + ((u >> 16) & 1u)) >> 16);
}
__device__ __forceinline__ void unp(u32 v, float& a, float& b){
  union { u32 i; float f; } c0, c1;
  c0.i = v << 16; c1.i = v & 0xffff0000u;
  a = c0.f; b = c1.f;
}
__device__ __forceinline__ float sigm(float x){ return 1.0f / (1.0f + __expf(-x)); }
__device__ __forceinline__ float softplusf(float x){ return fmaxf(x, 0.f) + log1pf(__expf(-fabsf(x))); }
__device__ __forceinline__ float wredsum(float v){
  #pragma unroll
  for (int o = 32; o > 0; o >>= 1) v += __shfl_down(v, o, 64);
  return v;
}
__device__ __forceinline__ float wredmax(float v){
  #pragma unroll
  for (int o = 32; o > 0; o >>= 1) v = fmaxf(v, __shfl_down(v, o, 64));
  return v;
}
__device__ __forceinline__ float ldval(const void* p, int idx, int dt32){
  return dt32 ? ((const float*)p)[idx] : bf2f(((const u16*)p)[idx]);
}

// ---- dtype detect (flag=1 -> fp32 tensors, 0 -> bf16) ----
__global__ void detect_dtype(const u16* __restrict__ buf, int* __restrict__ flag){
  int lane = threadIdx.x;
  float crazy = 0.f;
  for (int i = 0; i < 4; i++){
    u16 v = buf[lane * 4 + i];
    int e = (v >> 7) & 0xFF;
    if (e != 0 && (e < 117 || e > 137)) crazy += 1.f;
  }
  crazy = wredsum(crazy);
  if (lane == 0) flag[0] = (crazy >= 32.f) ? 1 : 0;
}

// identity-column pack: dst[k2*Jd + j] = bf16pair(W[j][2k2], W[j][2k2+1])
__global__ void pack_w(const void* __restrict__ src, u32* __restrict__ dst,
                       int Js, int Jd, int K, const int* __restrict__ flag){
  int j = blockIdx.x * 256 + threadIdx.x;
  int k2 = blockIdx.y;
  if (j >= Jd) return;
  u16 lo = 0, hi = 0;
  if (j < Js){
    if (flag[0]){
      const float* s = (const float*)src;
      lo = f2bf(s[(size_t)j * K + 2 * k2]);
      hi = f2bf(s[(size_t)j * K + 2 * k2 + 1]);
    } else {
      const u16* s = (const u16*)src;
      lo = s[(size_t)j * K + 2 * k2];
      hi = s[(size_t)j * K + 2 * k2 + 1];
    }
  }
  dst[(size_t)k2 * Jd + j] = (u32)lo | ((u32)hi << 16);
}

__device__ __forceinline__ int permctl(int c){
  // packed ctl col -> original interleaved col: [hE(128); rv r-major(512)]
  if (c < 128) return 5 * c;
  int q = c - 128; return 5 * (q & 127) + 1 + (q >> 7);
}
__device__ __forceinline__ int permout(int c){
  // packed out col -> original col: [h(128); rv r-major(512)]
  if (c < 128) return c;
  int q = c - 128; return 128 + 4 * (q & 127) + (q >> 7);
}

__global__ void pack_ctl(const void* __restrict__ src, u32* __restrict__ dst,
                         const int* __restrict__ flag){
  int j = blockIdx.x * 256 + threadIdx.x;
  int k2 = blockIdx.y;
  if (j >= 512) return;
  int c0 = permctl(2 * k2), c1 = permctl(2 * k2 + 1);
  u16 lo, hi;
  if (flag[0]){
    const float* s = (const float*)src;
    lo = f2bf(s[(size_t)j * 640 + c0]); hi = f2bf(s[(size_t)j * 640 + c1]);
  } else {
    const u16* s = (const u16*)src;
    lo = s[(size_t)j * 640 + c0]; hi = s[(size_t)j * 640 + c1];
  }
  dst[(size_t)k2 * 512 + j] = (u32)lo | ((u32)hi << 16);
}

__global__ void pack_out(const void* __restrict__ src, u32* __restrict__ dst,
                         const int* __restrict__ flag){
  int j = threadIdx.x;
  int k2 = blockIdx.y;
  if (j >= 128) return;
  int c0 = permout(2 * k2), c1 = permout(2 * k2 + 1);
  u16 lo, hi;
  if (flag[0]){
    const float* s = (const float*)src;
    lo = f2bf(s[(size_t)j * 640 + c0]); hi = f2bf(s[(size_t)j * 640 + c1]);
  } else {
    const u16* s = (const u16*)src;
    lo = s[(size_t)j * 640 + c0]; hi = s[(size_t)j * 640 + c1];
  }
  dst[(size_t)k2 * 128 + j] = (u32)lo | ((u32)hi << 16);
}

__global__ void fill_half(u16* __restrict__ p, int n){
  int i = blockIdx.x * 256 + threadIdx.x;
  if (i < n) p[i] = 0x3F00;
}

__global__ __launch_bounds__(NT) void dnc_main(
    const void* __restrict__ input,
    const void* __restrict__ enc_bih_g, const void* __restrict__ enc_bhh_g,
    const void* __restrict__ ctl_bih_g, const void* __restrict__ ctl_bhh_g,
    const void* __restrict__ iface_b_g, const void* __restrict__ out_b_g,
    const u32* __restrict__ encPW, const u32* __restrict__ ctlPW,
    const u32* __restrict__ ifPW, const u32* __restrict__ outPW,
    void* __restrict__ outp, const int* __restrict__ dtflag)
{
  const int bid = blockIdx.x;   // owner batch
  const int tid = threadIdx.x;
  const int lane = tid & 63;
  const int wid = tid >> 6;
  const int dt32 = dtflag[0];

  __shared__ __align__(16) float memS[Nv * 129];   // 66048 B
  __shared__ __align__(16) float linkS[Nv * 129];  // 66048 B
  __shared__ __align__(16) float pp[NT];
  __shared__ __align__(16) float ppE[512];
  __shared__ __align__(16) float xhC[768];   // [hE(128); rv r-major(512); hC(128)]
  __shared__ __align__(16) float xinS[128];  // staged next input column
  __shared__ __align__(16) float rkeyS[512], rwS[512], rcS[512];
  __shared__ __align__(16) float wkeyS[128], eraseS[128], wvecS[128];
  __shared__ __align__(16) float wwS[128], usageS[128], precS[128], wcS[128];
  __shared__ __align__(16) float uS[128], sortedU[128], scanA[128];
  __shared__ __align__(16) float encBias[512], ctlBias[512];
  __shared__ __align__(16) float outBias[128];
  __shared__ float rstrS[4], fgS[4], rmRaw[12], rmS[12], scal[8];

  // encoder-pointwise thread->w map (fixed across steps so cE reg persists)
  const int wE = (tid >= 919) ? (tid - 919) : (tid < 23 ? 105 + tid : -1);
  float cE = 0.f;   // encoder cell (only wE>=0 threads)
  float cC = 0.f;   // controller cell (only tid<128)

  // ---- init ----
  if (tid < 512){
    encBias[tid] = ldval(enc_bih_g, tid, dt32) + ldval(enc_bhh_g, tid, dt32);
    ctlBias[tid] = ldval(ctl_bih_g, tid, dt32) + ldval(ctl_bhh_g, tid, dt32);
    rwS[tid] = 0.f;
  }
  if (tid < 768) xhC[tid] = 0.f;
  if (tid < 128){
    outBias[tid] = ldval(out_b_g, tid, dt32);
    wwS[tid] = 0.f; usageS[tid] = 0.f; precS[tid] = 0.f;
  }
  for (int i = tid; i < Nv * 129; i += NT){ memS[i] = 0.f; linkS[i] = 0.f; }
  // stage x(0)
  if (tid < 64){
    int idx = (bid * Tv + 0) * Wv + 2 * tid;
    xinS[2 * tid] = ldval(input, idx, dt32);
    xinS[2 * tid + 1] = ldval(input, idx + 1, dt32);
  }
  __syncthreads();

  // ---- preamble: encoder step 0 ----
  if (tid >= 512){   // enc gates(0) = Wih*x(0) + Whh*0
    int o = tid - 512;
    const u32* wp = encPW + o;
    float a0 = 0.f, a1 = 0.f;
    #pragma unroll 8
    for (int k2 = 0; k2 < 64; k2++){
      float w0, w1; unp(wp[k2 * 512], w0, w1);
      float2 x2 = *(const float2*)(xinS + 2 * k2);
      a0 = fmaf(x2.x, w0, a0); a1 = fmaf(x2.y, w1, a1);
    }
    ppE[o] = a0 + a1;   // Whh part is zero (hE=0)
  }
  __syncthreads();
  if (wE >= 0){
    float g0 = ppE[wE] + encBias[wE];
    float g1 = ppE[128 + wE] + encBias[128 + wE];
    float g2 = ppE[256 + wE] + encBias[256 + wE];
    float g3 = ppE[384 + wE] + encBias[384 + wE];
    float cn = sigm(g1) * cE + sigm(g0) * tanhf(g2);
    cE = cn;
    xhC[wE] = sigm(g3) * tanhf(cn);   // hE(0)
  }
  if (tid >= 64 && tid < 128){   // stage x(1)
    int w2 = (tid - 64) * 2;
    int idx = (bid * Tv + 1) * Wv + w2;
    xinS[w2] = ldval(input, idx, dt32);
    xinS[w2 + 1] = ldval(input, idx + 1, dt32);
  }
  __syncthreads();

  // =========================== main loop ===========================
  for (int t = 0; t < Tv; ++t){
    // A: ctl gates GEMV (512 out x 2 k-split, K2=192 each), reg double-buffer
    {
      int o = tid & 511, s = tid >> 9;
      const u32* wp = ctlPW + (s * 192) * 512 + o;
      const float* xp = xhC + s * 384;
      float a0 = 0.f, a1 = 0.f;
      u32 wb[8];
      #pragma unroll
      for (int i = 0; i < 8; i++) wb[i] = wp[i * 512];
      #pragma unroll 1
      for (int c = 0; c < 184; c += 8){
        u32 wn[8];
        #pragma unroll
        for (int i = 0; i < 8; i++) wn[i] = wp[(c + 8 + i) * 512];
        #pragma unroll
        for (int i = 0; i < 8; i++){
          float w0, w1; unp(wb[i], w0, w1);
          float2 x2 = *(const float2*)(xp + 2 * (c + i));
          a0 = fmaf(x2.x, w0, a0); a1 = fmaf(x2.y, w1, a1);
          wb[i] = wn[i];
        }
      }
      #pragma unroll
      for (int i = 0; i < 8; i++){
        float w0, w1; unp(wb[i], w0, w1);
        float2 x2 = *(const float2*)(xp + 2 * (184 + i));
        a0 = fmaf(x2.x, w0, a0); a1 = fmaf(x2.y, w1, a1);
      }
      pp[tid] = a0 + a1;
    }
    __syncthreads();

    // B: ctl pointwise (tid<128)  ||  enc gates(t+1) GEMV (tids 512-1023)
    if (tid < 128){
      float g0 = pp[tid] + pp[512 + tid] + ctlBias[tid];
      float g1 = pp[128 + tid] + pp[640 + tid] + ctlBias[128 + tid];
      float g2 = pp[256 + tid] + pp[768 + tid] + ctlBias[256 + tid];
      float g3 = pp[384 + tid] + pp[896 + tid] + ctlBias[384 + tid];
      float cn = sigm(g1) * cC + sigm(g0) * tanhf(g2);
      cC = cn;
      xhC[640 + tid] = sigm(g3) * tanhf(cn);   // hC(t)
    } else if (tid >= 512){
      int o = tid - 512;
      const u32* wp = encPW + o;
      float a0 = 0.f, a1 = 0.f;
      // Wih * x(t+1) (from xinS), K2=64, double-buffered
      u32 wb[8];
      #pragma unroll
      for (int i = 0; i < 8; i++) wb[i] = wp[i * 512];
      #pragma unroll 1
      for (int c = 0; c < 56; c += 8){
        u32 wn[8];
        #pragma unroll
        for (int i = 0; i < 8; i++) wn[i] = wp[(c + 8 + i) * 512];
        #pragma unroll
        for (int i = 0; i < 8; i++){
          float w0, w1; unp(wb[i], w0, w1);
          float2 x2 = *(const float2*)(xinS + 2 * (c + i));
          a0 = fmaf(x2.x, w0, a0); a1 = fmaf(x2.y, w1, a1);
          wb[i] = wn[i];
        }
      }
      #pragma unroll
      for (int i = 0; i < 8; i++){
        float w0, w1; unp(wb[i], w0, w1);
        float2 x2 = *(const float2*)(xinS + 2 * (56 + i));
        a0 = fmaf(x2.x, w0, a0); a1 = fmaf(x2.y, w1, a1);
      }
      // Whh * hE(t) (from xhC[0..128)), K2=64
      const u32* wq = encPW + 64 * 512 + o;
      #pragma unroll
      for (int i = 0; i < 8; i++) wb[i] = wq[i * 512];
      #pragma unroll 1
      for (int c = 0; c < 56; c += 8){
        u32 wn[8];
        #pragma unroll
        for (int i = 0; i < 8; i++) wn[i] = wq[(c + 8 + i) * 512];
        #pragma unroll
        for (int i = 0; i < 8; i++){
          float w0, w1; unp(wb[i], w0, w1);
          float2 x2 = *(const float2*)(xhC + 2 * (c + i));
          a0 = fmaf(x2.x, w0, a0); a1 = fmaf(x2.y, w1, a1);
          wb[i] = wn[i];
        }
      }
      #pragma unroll
      for (int i = 0; i < 8; i++){
        float w0, w1; unp(wb[i], w0, w1);
        float2 x2 = *(const float2*)(xhC + 2 * (56 + i));
        a0 = fmaf(x2.x, w0, a0); a1 = fmaf(x2.y, w1, a1);
      }
      ppE[o] = a0 + a1;
    }
    __syncthreads();

    // C: iface GEMV (tids 0-918)  ||  enc pointwise -> hE(t+1) (wE threads)
    if (tid < 919){
      const u32* wp = ifPW + tid;
      const float* xp = xhC + 640;
      float a0 = ldval(iface_b_g, tid, dt32), a1 = 0.f;
      u32 wb[8];
      #pragma unroll
      for (int i = 0; i < 8; i++) wb[i] = wp[i * 928];
      #pragma unroll 1
      for (int c = 0; c < 56; c += 8){
        u32 wn[8];
        #pragma unroll
        for (int i = 0; i < 8; i++) wn[i] = wp[(c + 8 + i) * 928];
        #pragma unroll
        for (int i = 0; i < 8; i++){
          float w0, w1; unp(wb[i], w0, w1);
          float2 x2 = *(const float2*)(xp + 2 * (c + i));
          a0 = fmaf(x2.x, w0, a0); a1 = fmaf(x2.y, w1, a1);
          wb[i] = wn[i];
        }
      }
      #pragma unroll
      for (int i = 0; i < 8; i++){
        float w0, w1; unp(wb[i], w0, w1);
        float2 x2 = *(const float2*)(xp + 2 * (56 + i));
        a0 = fmaf(x2.x, w0, a0); a1 = fmaf(x2.y, w1, a1);
      }
      pp[tid] = a0 + a1;   // xi
    }
    if (wE >= 0){
      float g0 = ppE[wE] + encBias[wE];
      float g1 = ppE[128 + wE] + encBias[128 + wE];
      float g2 = ppE[256 + wE] + encBias[256 + wE];
      float g3 = ppE[384 + wE] + encBias[384 + wE];
      float cn = sigm(g1) * cE + sigm(g0) * tanhf(g2);
      cE = cn;
      xhC[wE] = sigm(g3) * tanhf(cn);   // hE(t+1)
    }
    __syncthreads();

    // D: parse xi (tid<919)  ||  stage x(t+2) (tids 928-991)
    if (tid < 919){
      float v = pp[tid];
      if (tid < 512) rkeyS[tid] = tanhf(v);
      else if (tid < 516) rstrS[tid - 512] = softplusf(v);
      else if (tid < 644) wkeyS[tid - 516] = tanhf(v);
      else if (tid == 644) scal[0] = softplusf(v);
      else if (tid < 773) eraseS[tid - 645] = sigm(v);
      else if (tid < 901) wvecS[tid - 773] = tanhf(v);
      else if (tid < 905) fgS[tid - 901] = sigm(v);
      else if (tid == 905) scal[1] = sigm(v);
      else if (tid == 906) scal[2] = sigm(v);
      else rmRaw[tid - 907] = v;
    } else if (tid >= 928 && tid < 992){
      int w2 = (tid - 928) * 2;
      int col = (t + 2 < Tv) ? t + 2 : Tv - 1;
      int idx = (bid * Tv + col) * Wv + w2;
      xinS[w2] = ldval(input, idx, dt32);
      xinS[w2 + 1] = ldval(input, idx + 1, dt32);
    }
    __syncthreads();

    // E: key norms (waves 0-4) || usage update (waves 5-6) || rm softmax
    if (wid < 5){
      float* arr = (wid < 4) ? (rkeyS + wid * 128) : wkeyS;
      float a = arr[lane], bq = arr[lane + 64];
      float s = wredsum(a * a + bq * bq);
      s = __shfl(s, 0, 64);
      float inv = 1.0f / (sqrtf(s) + DELTAv);
      arr[lane] = a * inv; arr[lane + 64] = bq * inv;
    } else if (wid < 7){
      int n = (wid - 5) * 64 + lane;
      float us = usageS[n];
      us = us + (1.f - us) * wwS[n];
      float ret = (1.f - fgS[0] * rwS[n]) * (1.f - fgS[1] * rwS[128 + n]) *
                  (1.f - fgS[2] * rwS[256 + n]) * (1.f - fgS[3] * rwS[384 + n]);
      usageS[n] = us * ret;
    } else if (tid >= 448 && tid < 452){
      int r = tid - 448;
      float m0 = rmRaw[3 * r], m1 = rmRaw[3 * r + 1], m2 = rmRaw[3 * r + 2];
      float mx = fmaxf(m0, fmaxf(m1, m2));
      float e0 = __expf(m0 - mx), e1 = __expf(m1 - mx), e2 = __expf(m2 - mx);
      float s = e0 + e1 + e2;
      rmS[3 * r] = e0 / s; rmS[3 * r + 1] = e1 / s; rmS[3 * r + 2] = e2 / s;
    }
    __syncthreads();

    // F: write-content dots (old mem, tid<128) + uS
    if (tid < 128){
      float sq = 0.f, dt = 0.f;
      #pragma unroll 8
      for (int j = 0; j < 128; j++){
        float m = memS[tid * 129 + j];
        sq = fmaf(m, m, sq); dt = fmaf(m, wkeyS[j], dt);
      }
      wcS[tid] = dt / (sqrtf(sq) + DELTAv) * scal[0];
    } else if (tid < 256){
      uS[tid - 128] = DELTAv + (1.f - DELTAv) * usageS[tid - 128];
    }
    __syncthreads();

    // G: wc softmax (wave 0) || stable rank (tids 64-191)
    int rnk = 0;
    if (wid == 0){
      float a = wcS[lane], bq = wcS[lane + 64];
      float mx = wredmax(fmaxf(a, bq)); mx = __shfl(mx, 0, 64);
      float ea = __expf(a - mx), eb = __expf(bq - mx);
      float s = wredsum(ea + eb); s = __shfl(s, 0, 64);
      wcS[lane] = ea / s; wcS[lane + 64] = eb / s;
    } else if (tid >= 64 && tid < 192){
      int n = tid - 64;
      float un = uS[n];
      int r = 0;
      for (int m = 0; m < 128; m++){
        float um = uS[m];
        r += (um < un) || (um == un && m < n);
      }
      rnk = r;
      sortedU[r] = un;
    }
    __syncthreads();

    // H: inclusive cumprod scan (wave 8)
    if (wid == 8){
      float a = sortedU[2 * lane], bq = sortedU[2 * lane + 1];
      float p = a * bq;
      float incl = p;
      #pragma unroll
      for (int o = 1; o < 64; o <<= 1){
        float tv = __shfl_up(incl, o, 64);
        if (lane >= o) incl *= tv;
      }
      float ex = __shfl_up(incl, 1, 64);
      if (lane == 0) ex = 1.f;
      scanA[2 * lane] = ex * a;
      scanA[2 * lane + 1] = ex * p;
    }
    __syncthreads();

    // I: allocation + write weighting
    if (tid >= 64 && tid < 192){
      int n = tid - 64;
      float ex = (rnk == 0) ? 1.f : scanA[rnk - 1];
      float al = (1.f - uS[n]) * ex;
      wwS[n] = scal[2] * (scal[1] * al + (1.f - scal[1]) * wcS[n]);
    }
    __syncthreads();

    // J: sum ww
    if (wid == 0){
      float s = wredsum(wwS[lane] + wwS[64 + lane]);
      if (lane == 0) scal[3] = s;
    }
    __syncthreads();

    // K: mem erase/write + link update (all LDS)
    #pragma unroll
    for (int it = 0; it < 16; it++){
      int e = it * NT + tid;
      int n = e >> 7, w = e & 127;
      float wwn = wwS[n];
      float m = memS[n * 129 + w];
      memS[n * 129 + w] = m * (1.f - wwn * eraseS[w]) + wwn * wvecS[w];
      float l = linkS[n * 129 + w];
      linkS[n * 129 + w] = (n == w) ? 0.f
        : ((1.f - wwn - wwS[w]) * l + wwn * precS[w]);
    }
    __syncthreads();

    // L: read-content dots (new mem, tid<128) + prec update
    if (tid < 128){
      float sq = 0.f, d0 = 0.f, d1 = 0.f, d2 = 0.f, d3 = 0.f;
      #pragma unroll 4
      for (int j = 0; j < 128; j++){
        float m = memS[tid * 129 + j];
        sq = fmaf(m, m, sq);
        d0 = fmaf(m, rkeyS[j], d0);
        d1 = fmaf(m, rkeyS[128 + j], d1);
        d2 = fmaf(m, rkeyS[256 + j], d2);
        d3 = fmaf(m, rkeyS[384 + j], d3);
      }
      float inv = 1.f / (sqrtf(sq) + DELTAv);
      rcS[tid]       = d0 * inv * rstrS[0];
      rcS[128 + tid] = d1 * inv * rstrS[1];
      rcS[256 + tid] = d2 * inv * rstrS[2];
      rcS[384 + tid] = d3 * inv * rstrS[3];
    } else if (tid < 256){
      int n = tid - 128;
      precS[n] = (1.f - scal[3]) * precS[n] + wwS[n];
    }
    __syncthreads();

    // M: rc softmax (waves 0-3)
    if (wid < 4){
      float a = rcS[wid * 128 + lane], bq = rcS[wid * 128 + 64 + lane];
      float mx = wredmax(fmaxf(a, bq)); mx = __shfl(mx, 0, 64);
      float ea = __expf(a - mx), eb = __expf(bq - mx);
      float s = wredsum(ea + eb); s = __shfl(s, 0, 64);
      rcS[wid * 128 + lane] = ea / s; rcS[wid * 128 + 64 + lane] = eb / s;
    }
    __syncthreads();

    // N: fw (tid<512) / bw (tid>=512), old rw, link in LDS (conflict-free both ways)
    if (tid < 512){
      int r = tid >> 7, i = tid & 127;
      const float* rwp = rwS + r * 128;
      float acc = 0.f;
      #pragma unroll 8
      for (int j = 0; j < 128; j++) acc = fmaf(rwp[j], linkS[i * 129 + j], acc);
      pp[tid] = acc;   // fw
    } else {
      int o = tid - 512; int r = o >> 7, i = o & 127;
      const float* rwp = rwS + r * 128;
      float acc = 0.f;
      #pragma unroll 8
      for (int j = 0; j < 128; j++) acc = fmaf(rwp[j], linkS[j * 129 + i], acc);
      pp[tid] = acc;   // bw
    }
    __syncthreads();

    // O: new read weights
    if (tid < 512){
      int r = tid >> 7;
      rwS[tid] = rmS[3 * r] * pp[512 + tid] + rmS[3 * r + 1] * pp[tid] + rmS[3 * r + 2] * rcS[tid];
    }
    __syncthreads();

    // P: rv partials (k-split over n)
    {
      int s = tid >> 9, o = tid & 511, r = o >> 7, w = o & 127;
      float acc = 0.f;
      #pragma unroll 8
      for (int q = 0; q < 64; q++){
        int n = s * 64 + q;
        acc = fmaf(rwS[r * 128 + n], memS[n * 129 + w], acc);
      }
      pp[tid] = acc;
    }
    __syncthreads();

    // Q: rv combine -> xhC rv slot (r-major)
    if (tid < 512) xhC[128 + tid] = pp[tid] + pp[512 + tid];
    __syncthreads();

    // R: output GEMV (128 out x 8 k-splits of 40 pairs)
    {
      int s8 = tid >> 7, j = tid & 127;
      const u32* wp = outPW + (s8 * 40) * 128 + j;
      float a0 = 0.f, a1 = 0.f;
      #pragma unroll 8
      for (int q = 0; q < 40; q++){
        int k2 = s8 * 40 + q;
        const float* xb = (k2 < 64) ? (xhC + 640 + 2 * k2) : (xhC + 2 * k2);
        float w0, w1; unp(wp[q * 128], w0, w1);
        a0 = fmaf(xb[0], w0, a0); a1 = fmaf(xb[1], w1, a1);
      }
      pp[tid] = a0 + a1;
    }
    __syncthreads();

    // S: store output
    if (tid < 128){
      float o = outBias[tid];
      #pragma unroll
      for (int s = 0; s < 8; s++) o += pp[s * 128 + tid];
      size_t oi = ((size_t)bid * Tv + t) * Wv + tid;
      if (dt32) ((float*)outp)[oi] = o;
      else ((u16*)outp)[oi] = f2bf(o);
    }
    __syncthreads();
  }
}

extern "C" void kernel_launch(void* const* d_in, const int* in_sizes, int n_in,
                              void* d_out, int out_size, void* d_ws, size_t ws_size,
                              hipStream_t stream) {
  (void)in_sizes; (void)n_in;
  const void* input   = d_in[0];
  const void* enc_Wih = d_in[2];
  const void* enc_Whh = d_in[3];
  const void* enc_bih = d_in[4];
  const void* enc_bhh = d_in[5];
  const void* ctl_Wih = d_in[6];
  const void* ctl_Whh = d_in[7];
  const void* ctl_bih = d_in[8];
  const void* ctl_bhh = d_in[9];
  const void* iface_W = d_in[10];
  const void* iface_b = d_in[11];
  const void* out_W   = d_in[12];
  const void* out_b   = d_in[13];

  char* ws = (char*)d_ws;
  size_t off = 0;
  int* dtflag = (int*)(ws + off); off += 256;
  u32* encPW  = (u32*)(ws + off); off += (size_t)128 * 512 * 4;   // [Wih k2 0..64 | Whh 64..128]
  u32* ctlPW  = (u32*)(ws + off); off += (size_t)384 * 512 * 4;   // [perm Wih 0..320 | Whh 320..384]
  u32* ifPW   = (u32*)(ws + off); off += (size_t)64 * 928 * 4;
  u32* outPW  = (u32*)(ws + off); off += (size_t)320 * 128 * 4;
  const size_t need_bytes = off;   // ~1.45 MB

  if (ws_size < need_bytes){
    fill_half<<<dim3((out_size + 255) / 256), dim3(256), 0, stream>>>((u16*)d_out, out_size);
    return;
  }

  detect_dtype<<<dim3(1), dim3(64), 0, stream>>>((const u16*)input, dtflag);

  pack_w<<<dim3(2, 64), 256, 0, stream>>>(enc_Wih, encPW, 512, 512, 128, dtflag);
  pack_w<<<dim3(2, 64), 256, 0, stream>>>(enc_Whh, encPW + 64 * 512, 512, 512, 128, dtflag);
  pack_ctl<<<dim3(2, 320), 256, 0, stream>>>(ctl_Wih, ctlPW, dtflag);
  pack_w<<<dim3(2, 64), 256, 0, stream>>>(ctl_Whh, ctlPW + 320 * 512, 512, 512, 128, dtflag);
  pack_w<<<dim3(4, 64), 256, 0, stream>>>(iface_W, ifPW, 919, 928, 128, dtflag);
  pack_out<<<dim3(1, 320), 128, 0, stream>>>(out_W, outPW, dtflag);

  dnc_main<<<dim3(Bv), dim3(NT), 0, stream>>>(
      input, enc_bih, enc_bhh, ctl_bih, ctl_bhh, iface_b, out_b,
      encPW, ctlPW, ifPW, outPW, d_out, dtflag);
}